// Round 6
// baseline (189.013 us; speedup 1.0000x reference)
//
#include <hip/hip_runtime.h>
#include <math.h>

#define N_   8192
#define IN_  512
#define ZD   128
#define CC   64
#define HD   50
#define EPSF 1e-8f

typedef float vf4 __attribute__((ext_vector_type(4)));
typedef __attribute__((ext_vector_type(8))) short bfrag;   // 8 bf16 = 4 VGPR

#define MFMA16(a, b, c) __builtin_amdgcn_mfma_f32_16x16x32_bf16((a), (b), (c), 0, 0, 0)

// hot path (neg-sum): fast hw exp/log. abs err ~1.2e-7/term into a mean of O(1).
__device__ __forceinline__ float softplus_hot(float t) {
    return fmaxf(t, 0.f) + __logf(1.f + __expf(-fabsf(t)));
}
// accurate path (T term): log(softplus+1e-8) needs tiny-value fidelity -> libm.
__device__ __forceinline__ float softplus_acc(float t) {
    return fmaxf(t, 0.f) + log1pf(expf(-fabsf(t)));
}
__device__ __forceinline__ unsigned short bf16_rn(float x) {
    unsigned int u = __float_as_uint(x);
    return (unsigned short)((u + 0x7fff + ((u >> 16) & 1)) >> 16);
}
__device__ __forceinline__ float bf16_f(unsigned short h) {
    return __uint_as_float(((unsigned int)h) << 16);
}
// cheap split: hi = bit-truncated bf16 (1 op), rem = v - hi is EXACT in fp32,
// lo = rn(rem). Residual ~2^-17 rel (vs 2^-18 with rn-hi) — both far below the
// dropped lo*lo MFMA term (~2^-16), so accuracy class is unchanged.
__device__ __forceinline__ void split8(const float* v, bfrag& hi, bfrag& lo) {
    #pragma unroll
    for (int e = 0; e < 8; ++e) {
        unsigned int u = __float_as_uint(v[e]);
        unsigned short h = (unsigned short)(u >> 16);
        ((short*)&hi)[e] = (short)h;
        ((short*)&lo)[e] = (short)bf16_rn(v[e] - bf16_f(h));
    }
}

// ============================================================================
// k_pre: 276 blocks, 256 threads (Ws lane rebalanced to 1 cat/block).
//   blocks 0..63    : per-category grouping
//   blocks 64..79   : W1^T bf16 hi/lo packed in MFMA B-frag order (4 k-chunks)
//   blocks 80..83   : W2^T bf16 hi/lo packed in MFMA B-frag order
//   blocks 84..211  : fz = z @ Wz + bz  fp32 (64 rows/block) + fz_hi epilogue
//   blocks 212..275 : Ws[cat] -> Wst_hi/lo [e][d] bf16 (1 cat per block)
// ============================================================================
__global__ __launch_bounds__(256) void k_pre(const int* __restrict__ c,
                                             const float* __restrict__ W1,
                                             const float* __restrict__ z,
                                             const float* __restrict__ Wz,
                                             const float* __restrict__ bz,
                                             const float* __restrict__ W2,
                                             const float* __restrict__ Ws,
                                             uint4* __restrict__ W1p,
                                             uint4* __restrict__ W2p,
                                             float* __restrict__ fz,
                                             unsigned short* __restrict__ fz_hi,
                                             unsigned short* __restrict__ Wst_hi,
                                             unsigned short* __restrict__ Wst_lo,
                                             int* __restrict__ counts,
                                             int* __restrict__ offsets,
                                             int* __restrict__ grouped) {
    __shared__ float smem[64 * 129];             // 33 KB union
    int tid = threadIdx.x;
    int b   = blockIdx.x;
    if (b < CC) {
        __shared__ int hist[CC];
        __shared__ int cursor;
        __shared__ int off_s;
        if (tid < CC) hist[tid] = 0;
        if (tid == 0) cursor = 0;
        __syncthreads();
        for (int i = tid; i < N_; i += 256) atomicAdd(&hist[c[i]], 1);
        __syncthreads();
        if (tid == 0) {
            int off = 0;
            for (int q = 0; q < b; ++q) off += hist[q];
            off_s = off;
            counts[b]  = hist[b];
            offsets[b] = off;
        }
        __syncthreads();
        int off = off_s;
        for (int i = tid; i < N_; i += 256) {
            if (c[i] == b) {
                int p = atomicAdd(&cursor, 1);
                grouped[off + p] = i;
            }
        }
    } else if (b < 80) {
        // ---- W1^T packed frags: unit = (kc, f, lane), 4096 units ----
        int unit = (b - 64) * 256 + tid;
        int lane = unit & 63, f = (unit >> 6) & 15, kc = unit >> 10;
        int nt = f >> 2, ks = f & 3;
        int n = nt * 16 + (lane & 15);           // h-col (0..63, pad >=50)
        int kbase = kc * 128 + ks * 32 + (lane >> 4) * 8;
        unsigned short hi8[8], lo8[8];
        #pragma unroll
        for (int j = 0; j < 8; ++j) {
            int k = kbase + j;
            float v = (n < HD) ? W1[k * HD + n] : 0.f;
            unsigned short h = bf16_rn(v);
            hi8[j] = h;
            lo8[j] = bf16_rn(v - bf16_f(h));
        }
        W1p[kc * 2048 + f * 64 + lane]        = *(uint4*)hi8;
        W1p[kc * 2048 + 1024 + f * 64 + lane] = *(uint4*)lo8;
    } else if (b < 84) {
        // ---- W2^T packed frags: unit = (f, lane), 1024 units ----
        int unit = (b - 80) * 256 + tid;
        int lane = unit & 63, f = unit >> 6;
        int nt = f >> 1, ks = f & 1;
        int n = nt * 16 + (lane & 15);           // fx-col (0..127)
        int kbase = ks * 32 + (lane >> 4) * 8;
        unsigned short hi8[8], lo8[8];
        #pragma unroll
        for (int j = 0; j < 8; ++j) {
            int k = kbase + j;
            float v = (k < HD) ? W2[k * ZD + n] : 0.f;
            unsigned short h = bf16_rn(v);
            hi8[j] = h;
            lo8[j] = bf16_rn(v - bf16_f(h));
        }
        W2p[f * 64 + lane]        = *(uint4*)hi8;
        W2p[1024 + f * 64 + lane] = *(uint4*)lo8;
    } else if (b < 212) {
        // ---- fz: 64 rows per block, 128 blocks ----
        float* sz = smem;                        // 64*128 floats
        int row0 = (b - 84) * 64;
        vf4* s4 = (vf4*)sz;
        const vf4* z4 = (const vf4*)(z + (size_t)row0 * ZD);
        #pragma unroll
        for (int f = 0; f < 8; ++f) s4[tid + f * 256] = z4[tid + f * 256];
        __syncthreads();
        int cp = tid & 31, rgp = tid >> 5;       // 8 row-groups x 8 rows
        const vf4* Wz4 = (const vf4*)Wz;
        vf4 bb = ((const vf4*)bz)[cp];
        vf4 acc[8];
        #pragma unroll
        for (int r = 0; r < 8; ++r) acc[r] = bb;
        #pragma unroll 1
        for (int d4 = 0; d4 < 32; ++d4) {
            vf4 w0 = Wz4[(4 * d4 + 0) * 32 + cp];
            vf4 w1 = Wz4[(4 * d4 + 1) * 32 + cp];
            vf4 w2 = Wz4[(4 * d4 + 2) * 32 + cp];
            vf4 w3 = Wz4[(4 * d4 + 3) * 32 + cp];
            #pragma unroll
            for (int r = 0; r < 8; ++r) {
                vf4 a = s4[(rgp * 8 + r) * 32 + d4];
                acc[r] += a[0] * w0;
                acc[r] += a[1] * w1;
                acc[r] += a[2] * w2;
                acc[r] += a[3] * w3;
            }
        }
        vf4* fz4 = (vf4*)fz;
        #pragma unroll
        for (int r = 0; r < 8; ++r) {
            int n = row0 + rgp * 8 + r;
            fz4[(size_t)n * 32 + cp] = acc[r];
            ushort4 h;
            h.x = bf16_rn(acc[r][0]); h.y = bf16_rn(acc[r][1]);
            h.z = bf16_rn(acc[r][2]); h.w = bf16_rn(acc[r][3]);
            *(ushort4*)(fz_hi + (size_t)n * ZD + cp * 4) = h;
        }
    } else {
        // ---- Ws transpose+split: 1 cat per block (halved critical path) ----
        int cat = b - 212;
        const float* Wc = Ws + (size_t)cat * ZD * ZD;
        unsigned short* Whi = Wst_hi + (size_t)cat * ZD * ZD;
        unsigned short* Wlo = Wst_lo + (size_t)cat * ZD * ZD;
        #pragma unroll 1
        for (int half = 0; half < 2; ++half) {
            __syncthreads();
            const vf4* src = (const vf4*)(Wc + (size_t)half * 64 * ZD);
            #pragma unroll
            for (int f = 0; f < 8; ++f) {        // 2048 vf4 = 64 rows x 32
                int idx = tid + f * 256;
                int row = idx >> 5, q = idx & 31;
                vf4 v = src[idx];
                #pragma unroll
                for (int e = 0; e < 4; ++e) smem[row * 129 + q * 4 + e] = v[e];
            }
            __syncthreads();
            #pragma unroll 1
            for (int f = 0; f < 32; ++f) {       // 8192 = 128 e x 64 dd
                int idx = tid + f * 256;
                int e = idx >> 6, dd = idx & 63;
                float v = smem[dd * 129 + e];
                unsigned short h = bf16_rn(v);
                Whi[(size_t)e * ZD + half * 64 + dd] = h;
                Wlo[(size_t)e * ZD + half * 64 + dd] = bf16_rn(v - bf16_f(h));
            }
        }
    }
}

// ============================================================================
// k_all v2: merged hfx+fused with latency-hiding (T14 issue-early/write-late):
//  - Wst tile loaded into 32 VGPR at kernel head; LDS-written only when A/B
//    regions free (hides 128 KB L2 read under all of stage X).
//  - per-kc x row chunk (8 float4) + W1p stage (4 uint4) loaded to regs
//    BEFORE the barrier; ds-writes after (hides HBM/L2 latency under stage).
//  - S loop: register double-buffer prefetch of next j-tile (grouped+fz_hi
//    gather chain overlaps current tile's MFMA+softplus).
//  - trunc-based split8 (~40% fewer VALU in the hot repack).
// Geometry unchanged from round 5 (512 blocks, 512 threads, 77 KB LDS,
// 2 blocks/CU). LDS: A[34816] sW2|sWhi|su  B[34816] sW1|fxlo|sWlo|sB
//                 C[8704] sh|fxhi  E[512] sRed
// ============================================================================
#define TI 8
__global__ __launch_bounds__(512) void k_all(const float* __restrict__ x,
                                             const uint4* __restrict__ W1p,
                                             const uint4* __restrict__ W2p,
                                             const float* __restrict__ b1,
                                             const float* __restrict__ b2,
                                             const unsigned short* __restrict__ Wst_hi,
                                             const unsigned short* __restrict__ Wst_lo,
                                             const float* __restrict__ fz,
                                             const unsigned short* __restrict__ fz_hi,
                                             const int* __restrict__ grouped,
                                             const int* __restrict__ offsets,
                                             const int* __restrict__ counts,
                                             float* __restrict__ out) {
    __shared__ __align__(16) unsigned char SM[78848];
    uint4* A4    = (uint4*)(SM);                 // 34816 B
    uint4* B4    = (uint4*)(SM + 34816);         // 34816 B
    float* shC   = (float*)(SM + 69632);         // 8704 B
    float* sRedF = (float*)(SM + 78336);         // 512 B

    int tid = threadIdx.x;
    int cat = blockIdx.x >> 3;
    int t   = blockIdx.x & (TI - 1);
    int off = offsets[cat], cnt = counts[cat];
    int i0 = t * 32;
    if (i0 >= cnt) return;
    int mI = min(32, cnt - i0);

    int lane = tid & 63, wave = tid >> 6;
    int m = lane & 15, quad = lane >> 4;
    int rg = wave & 1, ch = wave >> 1;           // ch == eh, 0..3

    // =================== Stage X: fx for this block's 32 gathered rows ======
    uint4* sW2 = A4;                             // 32 KB (hi 0..1023, lo 1024..)
    uint4* sW1 = B4;                             // 32 KB per k-chunk
    float* sh  = shC;                            // [32][68]

    #pragma unroll
    for (int f = 0; f < 4; ++f) sW2[tid + f * 512] = W2p[tid + f * 512];

    // issue-early: Wst tile -> regs, consumed after stage X (write-late)
    const uint4* gh = (const uint4*)(Wst_hi + (size_t)cat * ZD * ZD);
    const uint4* gl = (const uint4*)(Wst_lo + (size_t)cat * ZD * ZD);
    uint4 wh[4], wl[4];
    #pragma unroll
    for (int f = 0; f < 4; ++f) {
        wh[f] = gh[tid + f * 512];
        wl[f] = gl[tid + f * 512];
    }

    int irowA = rg * 16 + m;
    int n_gA = grouped[off + i0 + min(irowA, mI - 1)];
    const float4* xr = (const float4*)(x + (size_t)n_gA * IN_);

    vf4 accP = {0.f, 0.f, 0.f, 0.f};
    vf4 accQ = {0.f, 0.f, 0.f, 0.f};
    vf4 accR = {0.f, 0.f, 0.f, 0.f};

    #pragma unroll 1
    for (int kc = 0; kc < 4; ++kc) {
        // issue this kc's x chunk + W1p chunk BEFORE the barrier
        float4 xa[4], xb[4];
        #pragma unroll
        for (int ks = 0; ks < 4; ++ks) {
            xa[ks] = xr[kc * 32 + ks * 8 + quad * 2];
            xb[ks] = xr[kc * 32 + ks * 8 + quad * 2 + 1];
        }
        uint4 w1r[4];
        #pragma unroll
        for (int f = 0; f < 4; ++f) w1r[f] = W1p[kc * 2048 + tid + f * 512];
        __syncthreads();                         // prev kc's sW1 reads done
        #pragma unroll
        for (int f = 0; f < 4; ++f) sW1[tid + f * 512] = w1r[f];
        __syncthreads();
        #pragma unroll 1
        for (int ks = 0; ks < 4; ++ks) {
            float xv[8] = {xa[ks].x, xa[ks].y, xa[ks].z, xa[ks].w,
                           xb[ks].x, xb[ks].y, xb[ks].z, xb[ks].w};
            bfrag ah, al;
            split8(xv, ah, al);
            bfrag bh = *(const bfrag*)&sW1[(ch * 4 + ks) * 64 + lane];
            bfrag bl = *(const bfrag*)&sW1[1024 + (ch * 4 + ks) * 64 + lane];
            accP = MFMA16(ah, bh, accP);
            accQ = MFMA16(ah, bl, accQ);
            accR = MFMA16(al, bh, accR);
        }
    }
    // bias + relu -> sh (rows 0..31, cols 0..63); waves disjoint in (rg, ch)
    {
        int col = ch * 16 + m;
        float bb = (col < HD) ? b1[col] : 0.f;
        vf4 acc = accP + accQ + accR;
        #pragma unroll
        for (int r = 0; r < 4; ++r)
            sh[(rg * 16 + quad * 4 + r) * 68 + col] = fmaxf(acc[r] + bb, 0.f);
    }
    __syncthreads();

    // phase B A-frags: row = rg*16+m, k = ks*32+quad*8..+8
    bfrag ah2[2], al2[2];
    #pragma unroll
    for (int ks = 0; ks < 2; ++ks) {
        const float4* shp = (const float4*)&sh[(rg * 16 + m) * 68 + ks * 32 + quad * 8];
        float4 ha = shp[0], hb = shp[1];
        float hv[8] = {ha.x, ha.y, ha.z, ha.w, hb.x, hb.y, hb.z, hb.w};
        split8(hv, ah2[ks], al2[ks]);
    }
    __syncthreads();                             // all sh reads done; C reusable

    // phase B: fx -> LDS tiles [32][136] (hi in C, lo in B; B=sW1 is free)
    unsigned short* fxhiT = (unsigned short*)shC;
    unsigned short* fxloT = (unsigned short*)B4;
    #pragma unroll
    for (int nt2 = 0; nt2 < 2; ++nt2) {
        int nt = ch * 2 + nt2;
        bfrag bh0 = *(const bfrag*)&sW2[(nt * 2 + 0) * 64 + lane];
        bfrag bl0 = *(const bfrag*)&sW2[1024 + (nt * 2 + 0) * 64 + lane];
        bfrag bh1 = *(const bfrag*)&sW2[(nt * 2 + 1) * 64 + lane];
        bfrag bl1 = *(const bfrag*)&sW2[1024 + (nt * 2 + 1) * 64 + lane];
        vf4 aA = {0.f, 0.f, 0.f, 0.f}, aB = {0.f, 0.f, 0.f, 0.f};
        aA = MFMA16(ah2[0], bh0, aA);
        aA = MFMA16(ah2[0], bl0, aA);
        aA = MFMA16(al2[0], bh0, aA);
        aB = MFMA16(ah2[1], bh1, aB);
        aB = MFMA16(ah2[1], bl1, aB);
        aB = MFMA16(al2[1], bh1, aB);
        vf4 a2 = aA + aB;
        int colB = nt * 16 + m;
        float bb2 = b2[colB];
        #pragma unroll
        for (int r = 0; r < 4; ++r) {
            int row = rg * 16 + quad * 4 + r;
            float v = a2[r] + bb2;
            unsigned int u = __float_as_uint(v);
            unsigned short hh = (unsigned short)(u >> 16);   // trunc split
            fxhiT[row * 136 + colB] = hh;
            fxloT[row * 136 + colB] = bf16_rn(v - bf16_f(hh));
        }
    }
    __syncthreads();

    // =================== Stage F (round-3 k_fused geometry) =================
    int eh = ch;
    bfrag a_hi[4], a_lo[4];
    #pragma unroll
    for (int kb = 0; kb < 4; ++kb) {
        a_hi[kb] = *(const bfrag*)&fxhiT[(rg * 16 + m) * 136 + kb * 32 + quad * 8];
        a_lo[kb] = *(const bfrag*)&fxloT[(rg * 16 + m) * 136 + kb * 32 + quad * 8];
    }
    __syncthreads();                             // frag reads done; A/B reusable

    // write-late: Wst regs -> LDS (no global wait here, data already in regs)
    uint4* sWhi = A4;
    uint4* sWlo = B4;
    #pragma unroll
    for (int f = 0; f < 4; ++f) {
        int idx = tid + f * 512;
        int e = idx >> 4, q = idx & 15;
        sWhi[e * 17 + q] = wh[f];
        sWlo[e * 17 + q] = wl[f];
    }
    __syncthreads();

    // phase U: wave owns et = eh*2 + {0,1}; 3 independent chains each
    vf4 uacc[2];
    #pragma unroll 1
    for (int et2 = 0; et2 < 2; ++et2) {
        int et = eh * 2 + et2;
        vf4 aH = {0.f, 0.f, 0.f, 0.f};
        vf4 aM = {0.f, 0.f, 0.f, 0.f};
        vf4 aL = {0.f, 0.f, 0.f, 0.f};
        #pragma unroll
        for (int kb = 0; kb < 4; ++kb) {
            bfrag bh = *(const bfrag*)&sWhi[(et * 16 + m) * 17 + kb * 4 + quad];
            bfrag bl = *(const bfrag*)&sWlo[(et * 16 + m) * 17 + kb * 4 + quad];
            aH = MFMA16(a_hi[kb], bh, aH);
            aM = MFMA16(a_hi[kb], bl, aM);
            aL = MFMA16(a_lo[kb], bh, aL);
        }
        uacc[et2] = aH + aM + aL;
    }

    int nrow[4];
    #pragma unroll
    for (int r = 0; r < 4; ++r) {
        int ir = rg * 16 + quad * 4 + r;
        nrow[r] = (ir < mI) ? grouped[off + i0 + ir] : -1;
    }
    // phase T: batched fz prefetch, partial over wave's 2 et
    float fzv[2][4];
    #pragma unroll
    for (int et2 = 0; et2 < 2; ++et2) {
        #pragma unroll
        for (int r = 0; r < 4; ++r) {
            fzv[et2][r] = 0.f;
            if (nrow[r] >= 0)
                fzv[et2][r] = fz[(size_t)nrow[r] * ZD + (eh * 2 + et2) * 16 + m];
        }
    }
    float p[4] = {0.f, 0.f, 0.f, 0.f};
    #pragma unroll
    for (int et2 = 0; et2 < 2; ++et2) {
        #pragma unroll
        for (int r = 0; r < 4; ++r) p[r] += uacc[et2][r] * fzv[et2][r];
    }
    #pragma unroll
    for (int r = 0; r < 4; ++r) {
        float v = p[r];
        #pragma unroll
        for (int s = 8; s >= 1; s >>= 1) v += __shfl_xor(v, s, 64);
        p[r] = v;
    }
    if (m == 0) {
        #pragma unroll
        for (int r = 0; r < 4; ++r)
            sRedF[(rg * 4 + eh) * 16 + quad * 4 + r] = p[r];
    }
    __syncthreads();                             // pT visible; A free -> su

    unsigned short* su = (unsigned short*)A4;    // [row][e], stride 136
    #pragma unroll
    for (int et2 = 0; et2 < 2; ++et2) {
        int col = (eh * 2 + et2) * 16 + m;
        #pragma unroll
        for (int r = 0; r < 4; ++r)
            su[(rg * 16 + quad * 4 + r) * 136 + col] = bf16_rn(uacc[et2][r]);
    }
    float logT_r[4] = {0.f, 0.f, 0.f, 0.f};
    if (eh == 0) {
        #pragma unroll
        for (int r = 0; r < 4; ++r) {
            float pt = sRedF[(rg * 4 + 0) * 16 + quad * 4 + r]
                     + sRedF[(rg * 4 + 1) * 16 + quad * 4 + r]
                     + sRedF[(rg * 4 + 2) * 16 + quad * 4 + r]
                     + sRedF[(rg * 4 + 3) * 16 + quad * 4 + r];
            logT_r[r] = logf(softplus_acc(pt) + EPSF);
        }
    }
    __syncthreads();                             // su visible

    bfrag na[4];
    #pragma unroll
    for (int kb = 0; kb < 4; ++kb)
        na[kb] = *(const bfrag*)&su[(rg * 16 + m) * 136 + kb * 32 + quad * 8];

    uint4* sB = B4;                              // [64][17]; B free after U
    float negsum[4] = {0.f, 0.f, 0.f, 0.f};
    int jr_s = tid >> 4, q_s = tid & 15;         // staging row/col

    // prefetch j-tile 0 into regs
    uint4 pf[2];
    {
        int mJ0 = min(64, cnt);
        #pragma unroll
        for (int f = 0; f < 2; ++f) {
            int jr = jr_s + f * 32;
            uint4 v = {0u, 0u, 0u, 0u};
            if (jr < mJ0) {
                int j_g = grouped[off + jr];
                v = *(const uint4*)(fz_hi + (size_t)j_g * ZD + q_s * 8);
            }
            pf[f] = v;
        }
    }

    #pragma unroll 1
    for (int jb = 0; jb < cnt; jb += 64) {
        int mJ = min(64, cnt - jb);
        __syncthreads();                         // prev tile's sB reads done
        #pragma unroll
        for (int f = 0; f < 2; ++f) sB[(jr_s + f * 32) * 17 + q_s] = pf[f];
        // issue next tile's gather chain (overlaps this tile's compute)
        int jn = jb + 64;
        if (jn < cnt) {
            int mJn = min(64, cnt - jn);
            #pragma unroll
            for (int f = 0; f < 2; ++f) {
                int jr = jr_s + f * 32;
                uint4 v = {0u, 0u, 0u, 0u};
                if (jr < mJn) {
                    int j_g = grouped[off + jn + jr];
                    v = *(const uint4*)(fz_hi + (size_t)j_g * ZD + q_s * 8);
                }
                pf[f] = v;
            }
        }
        __syncthreads();
        {
            int jt = eh;                         // wave owns one 16-wide j-tile
            bfrag b0 = *(const bfrag*)&sB[(jt * 16 + m) * 17 + 0 + quad];
            bfrag b1 = *(const bfrag*)&sB[(jt * 16 + m) * 17 + 4 + quad];
            bfrag b2 = *(const bfrag*)&sB[(jt * 16 + m) * 17 + 8 + quad];
            bfrag b3 = *(const bfrag*)&sB[(jt * 16 + m) * 17 + 12 + quad];
            vf4 aA = {0.f, 0.f, 0.f, 0.f}, aB = {0.f, 0.f, 0.f, 0.f};
            aA = MFMA16(na[0], b0, aA);
            aA = MFMA16(na[1], b1, aA);
            aB = MFMA16(na[2], b2, aB);
            aB = MFMA16(na[3], b3, aB);
            vf4 acc = aA + aB;
            bool jok = (jt * 16 + m) < mJ;
            #pragma unroll
            for (int r = 0; r < 4; ++r)
                if (jok) negsum[r] += softplus_hot(acc[r]);
        }
    }

    #pragma unroll
    for (int r = 0; r < 4; ++r) {
        float v = negsum[r];
        #pragma unroll
        for (int s = 8; s >= 1; s >>= 1) v += __shfl_xor(v, s, 64);
        negsum[r] = v;
    }
    if (m == 0) {
        #pragma unroll
        for (int r = 0; r < 4; ++r)
            sRedF[(rg * 4 + eh) * 16 + quad * 4 + r] = negsum[r];
    }
    __syncthreads();
    if (eh == 0 && m == 0) {
        #pragma unroll
        for (int r = 0; r < 4; ++r) {
            if (nrow[r] >= 0) {
                float tot = sRedF[(rg * 4 + 0) * 16 + quad * 4 + r]
                          + sRedF[(rg * 4 + 1) * 16 + quad * 4 + r]
                          + sRedF[(rg * 4 + 2) * 16 + quad * 4 + r]
                          + sRedF[(rg * 4 + 3) * 16 + quad * 4 + r];
                out[nrow[r]] = logT_r[r] - logf(tot / (float)cnt + EPSF);
            }
        }
    }
}

extern "C" void kernel_launch(void* const* d_in, const int* in_sizes, int n_in,
                              void* d_out, int out_size, void* d_ws, size_t ws_size,
                              hipStream_t stream) {
    const float* x  = (const float*)d_in[0];
    const int*   c  = (const int*)  d_in[1];
    const float* z  = (const float*)d_in[2];
    const float* W1 = (const float*)d_in[3];
    const float* b1 = (const float*)d_in[4];
    const float* W2 = (const float*)d_in[5];
    const float* b2 = (const float*)d_in[6];
    const float* Wz = (const float*)d_in[7];
    const float* bz = (const float*)d_in[8];
    const float* Ws = (const float*)d_in[9];
    float* out = (float*)d_out;

    uint4* W1p = (uint4*)d_ws;                         // 8192 uint4 (128 KB)
    uint4* W2p = W1p + 8192;                           // 2048 uint4 (32 KB)
    float* fz  = (float*)(W2p + 2048);                 // N*128 f
    unsigned short* fz_hi  = (unsigned short*)(fz + (size_t)N_ * ZD);
    unsigned short* Wst_hi = fz_hi + (size_t)N_ * ZD;  // CC*128*128
    unsigned short* Wst_lo = Wst_hi + (size_t)CC * ZD * ZD;
    int* counts  = (int*)(Wst_lo + (size_t)CC * ZD * ZD);
    int* offsets = counts + CC;
    int* grouped = offsets + CC;

    k_pre <<<276, 256, 0, stream>>>(c, W1, z, Wz, bz, W2, Ws, W1p, W2p, fz,
                                    fz_hi, Wst_hi, Wst_lo, counts, offsets,
                                    grouped);
    k_all <<<CC * TI, 512, 0, stream>>>(x, W1p, W2p, b1, b2, Wst_hi, Wst_lo,
                                        fz, fz_hi, grouped, offsets, counts,
                                        out);
}

// Round 7
// 131.107 us; speedup vs baseline: 1.4417x; 1.4417x over previous
//
#include <hip/hip_runtime.h>
#include <math.h>

#define N_   8192
#define IN_  512
#define ZD   128
#define CC   64
#define HD   50
#define EPSF 1e-8f

typedef float vf4 __attribute__((ext_vector_type(4)));
typedef __attribute__((ext_vector_type(8))) short bfrag;   // 8 bf16 = 4 VGPR

#define MFMA16(a, b, c) __builtin_amdgcn_mfma_f32_16x16x32_bf16((a), (b), (c), 0, 0, 0)

// hot path (neg-sum): fast hw exp/log. abs err ~1.2e-7/term into a mean of O(1).
__device__ __forceinline__ float softplus_hot(float t) {
    return fmaxf(t, 0.f) + __logf(1.f + __expf(-fabsf(t)));
}
// accurate path (T term): log(softplus+1e-8) needs tiny-value fidelity -> libm.
__device__ __forceinline__ float softplus_acc(float t) {
    return fmaxf(t, 0.f) + log1pf(expf(-fabsf(t)));
}
__device__ __forceinline__ unsigned short bf16_rn(float x) {
    unsigned int u = __float_as_uint(x);
    return (unsigned short)((u + 0x7fff + ((u >> 16) & 1)) >> 16);
}
__device__ __forceinline__ float bf16_f(unsigned short h) {
    return __uint_as_float(((unsigned int)h) << 16);
}
// cheap split: hi = bit-truncated bf16 (1 op), rem = v - hi EXACT in fp32,
// lo = rn(rem). Residual class unchanged vs rn-split (both << dropped lo*lo).
__device__ __forceinline__ void split8(const float* v, bfrag& hi, bfrag& lo) {
    #pragma unroll
    for (int e = 0; e < 8; ++e) {
        unsigned int u = __float_as_uint(v[e]);
        unsigned short h = (unsigned short)(u >> 16);
        ((short*)&hi)[e] = (short)h;
        ((short*)&lo)[e] = (short)bf16_rn(v[e] - bf16_f(h));
    }
}

// ============================================================================
// k_pre: 276 blocks, 256 threads (proven; Ws lane = 1 cat/block).
//   blocks 0..63    : per-category grouping
//   blocks 64..79   : W1^T bf16 hi/lo packed in MFMA B-frag order (4 k-chunks)
//   blocks 80..83   : W2^T bf16 hi/lo packed in MFMA B-frag order
//   blocks 84..211  : fz = z @ Wz + bz  fp32 (64 rows/block) + fz_hi epilogue
//   blocks 212..275 : Ws[cat] -> Wst_hi/lo [e][d] bf16 (1 cat per block)
// ============================================================================
__global__ __launch_bounds__(256) void k_pre(const int* __restrict__ c,
                                             const float* __restrict__ W1,
                                             const float* __restrict__ z,
                                             const float* __restrict__ Wz,
                                             const float* __restrict__ bz,
                                             const float* __restrict__ W2,
                                             const float* __restrict__ Ws,
                                             uint4* __restrict__ W1p,
                                             uint4* __restrict__ W2p,
                                             float* __restrict__ fz,
                                             unsigned short* __restrict__ fz_hi,
                                             unsigned short* __restrict__ Wst_hi,
                                             unsigned short* __restrict__ Wst_lo,
                                             int* __restrict__ counts,
                                             int* __restrict__ offsets,
                                             int* __restrict__ grouped) {
    __shared__ float smem[64 * 129];             // 33 KB union
    int tid = threadIdx.x;
    int b   = blockIdx.x;
    if (b < CC) {
        __shared__ int hist[CC];
        __shared__ int cursor;
        __shared__ int off_s;
        if (tid < CC) hist[tid] = 0;
        if (tid == 0) cursor = 0;
        __syncthreads();
        for (int i = tid; i < N_; i += 256) atomicAdd(&hist[c[i]], 1);
        __syncthreads();
        if (tid == 0) {
            int off = 0;
            for (int q = 0; q < b; ++q) off += hist[q];
            off_s = off;
            counts[b]  = hist[b];
            offsets[b] = off;
        }
        __syncthreads();
        int off = off_s;
        for (int i = tid; i < N_; i += 256) {
            if (c[i] == b) {
                int p = atomicAdd(&cursor, 1);
                grouped[off + p] = i;
            }
        }
    } else if (b < 80) {
        // ---- W1^T packed frags: unit = (kc, f, lane), 4096 units ----
        int unit = (b - 64) * 256 + tid;
        int lane = unit & 63, f = (unit >> 6) & 15, kc = unit >> 10;
        int nt = f >> 2, ks = f & 3;
        int n = nt * 16 + (lane & 15);           // h-col (0..63, pad >=50)
        int kbase = kc * 128 + ks * 32 + (lane >> 4) * 8;
        unsigned short hi8[8], lo8[8];
        #pragma unroll
        for (int j = 0; j < 8; ++j) {
            int k = kbase + j;
            float v = (n < HD) ? W1[k * HD + n] : 0.f;
            unsigned short h = bf16_rn(v);
            hi8[j] = h;
            lo8[j] = bf16_rn(v - bf16_f(h));
        }
        W1p[kc * 2048 + f * 64 + lane]        = *(uint4*)hi8;
        W1p[kc * 2048 + 1024 + f * 64 + lane] = *(uint4*)lo8;
    } else if (b < 84) {
        // ---- W2^T packed frags: unit = (f, lane), 1024 units ----
        int unit = (b - 80) * 256 + tid;
        int lane = unit & 63, f = unit >> 6;
        int nt = f >> 1, ks = f & 1;
        int n = nt * 16 + (lane & 15);           // fx-col (0..127)
        int kbase = ks * 32 + (lane >> 4) * 8;
        unsigned short hi8[8], lo8[8];
        #pragma unroll
        for (int j = 0; j < 8; ++j) {
            int k = kbase + j;
            float v = (k < HD) ? W2[k * ZD + n] : 0.f;
            unsigned short h = bf16_rn(v);
            hi8[j] = h;
            lo8[j] = bf16_rn(v - bf16_f(h));
        }
        W2p[f * 64 + lane]        = *(uint4*)hi8;
        W2p[1024 + f * 64 + lane] = *(uint4*)lo8;
    } else if (b < 212) {
        // ---- fz: 64 rows per block, 128 blocks ----
        float* sz = smem;                        // 64*128 floats
        int row0 = (b - 84) * 64;
        vf4* s4 = (vf4*)sz;
        const vf4* z4 = (const vf4*)(z + (size_t)row0 * ZD);
        #pragma unroll
        for (int f = 0; f < 8; ++f) s4[tid + f * 256] = z4[tid + f * 256];
        __syncthreads();
        int cp = tid & 31, rgp = tid >> 5;       // 8 row-groups x 8 rows
        const vf4* Wz4 = (const vf4*)Wz;
        vf4 bb = ((const vf4*)bz)[cp];
        vf4 acc[8];
        #pragma unroll
        for (int r = 0; r < 8; ++r) acc[r] = bb;
        #pragma unroll 1
        for (int d4 = 0; d4 < 32; ++d4) {
            vf4 w0 = Wz4[(4 * d4 + 0) * 32 + cp];
            vf4 w1 = Wz4[(4 * d4 + 1) * 32 + cp];
            vf4 w2 = Wz4[(4 * d4 + 2) * 32 + cp];
            vf4 w3 = Wz4[(4 * d4 + 3) * 32 + cp];
            #pragma unroll
            for (int r = 0; r < 8; ++r) {
                vf4 a = s4[(rgp * 8 + r) * 32 + d4];
                acc[r] += a[0] * w0;
                acc[r] += a[1] * w1;
                acc[r] += a[2] * w2;
                acc[r] += a[3] * w3;
            }
        }
        vf4* fz4 = (vf4*)fz;
        #pragma unroll
        for (int r = 0; r < 8; ++r) {
            int n = row0 + rgp * 8 + r;
            fz4[(size_t)n * 32 + cp] = acc[r];
            ushort4 h;
            h.x = bf16_rn(acc[r][0]); h.y = bf16_rn(acc[r][1]);
            h.z = bf16_rn(acc[r][2]); h.w = bf16_rn(acc[r][3]);
            *(ushort4*)(fz_hi + (size_t)n * ZD + cp * 4) = h;
        }
    } else {
        // ---- Ws transpose+split: 1 cat per block ----
        int cat = b - 212;
        const float* Wc = Ws + (size_t)cat * ZD * ZD;
        unsigned short* Whi = Wst_hi + (size_t)cat * ZD * ZD;
        unsigned short* Wlo = Wst_lo + (size_t)cat * ZD * ZD;
        #pragma unroll 1
        for (int half = 0; half < 2; ++half) {
            __syncthreads();
            const vf4* src = (const vf4*)(Wc + (size_t)half * 64 * ZD);
            #pragma unroll
            for (int f = 0; f < 8; ++f) {        // 2048 vf4 = 64 rows x 32
                int idx = tid + f * 256;
                int row = idx >> 5, q = idx & 31;
                vf4 v = src[idx];
                #pragma unroll
                for (int e = 0; e < 4; ++e) smem[row * 129 + q * 4 + e] = v[e];
            }
            __syncthreads();
            #pragma unroll 1
            for (int f = 0; f < 32; ++f) {       // 8192 = 128 e x 64 dd
                int idx = tid + f * 256;
                int e = idx >> 6, dd = idx & 63;
                float v = smem[dd * 129 + e];
                unsigned short h = bf16_rn(v);
                Whi[(size_t)e * ZD + half * 64 + dd] = h;
                Wlo[(size_t)e * ZD + half * 64 + dd] = bf16_rn(v - bf16_f(h));
            }
        }
    }
}

// ============================================================================
// k_all v3: round-5 structure (proven 132 µs) + spill-safe refinements only:
//  - ks loop FULLY UNROLLED with direct x loads (static indices, no arrays ->
//    no scratch; compiler hoists all 8 loads to top of each kc body).
//  - W1p staged via w1r[4] regs issue-early/write-late (static unroll, safe).
//  - trunc split8. S-loop j-tile register prefetch pf[2] (static, safe).
//  - Wst staged directly global->LDS (round-5 style; NO long-live-range regs).
// Round-6's scratch-spill lesson: no runtime-indexed register arrays.
// ============================================================================
#define TI 8
__global__ __launch_bounds__(512) void k_all(const float* __restrict__ x,
                                             const uint4* __restrict__ W1p,
                                             const uint4* __restrict__ W2p,
                                             const float* __restrict__ b1,
                                             const float* __restrict__ b2,
                                             const unsigned short* __restrict__ Wst_hi,
                                             const unsigned short* __restrict__ Wst_lo,
                                             const float* __restrict__ fz,
                                             const unsigned short* __restrict__ fz_hi,
                                             const int* __restrict__ grouped,
                                             const int* __restrict__ offsets,
                                             const int* __restrict__ counts,
                                             float* __restrict__ out) {
    __shared__ __align__(16) unsigned char SM[78848];
    uint4* A4    = (uint4*)(SM);                 // 34816 B
    uint4* B4    = (uint4*)(SM + 34816);         // 34816 B
    float* shC   = (float*)(SM + 69632);         // 8704 B
    float* sRedF = (float*)(SM + 78336);         // 512 B

    int tid = threadIdx.x;
    int cat = blockIdx.x >> 3;
    int t   = blockIdx.x & (TI - 1);
    int off = offsets[cat], cnt = counts[cat];
    int i0 = t * 32;
    if (i0 >= cnt) return;
    int mI = min(32, cnt - i0);

    int lane = tid & 63, wave = tid >> 6;
    int m = lane & 15, quad = lane >> 4;
    int rg = wave & 1, ch = wave >> 1;           // ch == eh, 0..3

    // =================== Stage X: fx for this block's 32 gathered rows ======
    uint4* sW2 = A4;                             // 32 KB (hi 0..1023, lo 1024..)
    uint4* sW1 = B4;                             // 32 KB per k-chunk
    float* sh  = shC;                            // [32][68]

    #pragma unroll
    for (int f = 0; f < 4; ++f) sW2[tid + f * 512] = W2p[tid + f * 512];

    int irowA = rg * 16 + m;
    int n_gA = grouped[off + i0 + min(irowA, mI - 1)];
    const float4* xr = (const float4*)(x + (size_t)n_gA * IN_);

    vf4 accP = {0.f, 0.f, 0.f, 0.f};
    vf4 accQ = {0.f, 0.f, 0.f, 0.f};
    vf4 accR = {0.f, 0.f, 0.f, 0.f};

    #pragma unroll 1
    for (int kc = 0; kc < 4; ++kc) {
        // issue-early: this kc's W1p chunk -> regs (static indices, no spill)
        uint4 w1r0 = W1p[kc * 2048 + tid];
        uint4 w1r1 = W1p[kc * 2048 + tid + 512];
        uint4 w1r2 = W1p[kc * 2048 + tid + 1024];
        uint4 w1r3 = W1p[kc * 2048 + tid + 1536];
        __syncthreads();                         // prev kc's sW1 reads done
        sW1[tid]        = w1r0;
        sW1[tid + 512]  = w1r1;
        sW1[tid + 1024] = w1r2;
        sW1[tid + 1536] = w1r3;
        __syncthreads();
        #pragma unroll
        for (int ks = 0; ks < 4; ++ks) {         // FULL unroll: loads hoisted
            float4 xa = xr[kc * 32 + ks * 8 + quad * 2];
            float4 xb = xr[kc * 32 + ks * 8 + quad * 2 + 1];
            float xv[8] = {xa.x, xa.y, xa.z, xa.w, xb.x, xb.y, xb.z, xb.w};
            bfrag ah, al;
            split8(xv, ah, al);
            bfrag bh = *(const bfrag*)&sW1[(ch * 4 + ks) * 64 + lane];
            bfrag bl = *(const bfrag*)&sW1[1024 + (ch * 4 + ks) * 64 + lane];
            accP = MFMA16(ah, bh, accP);
            accQ = MFMA16(ah, bl, accQ);
            accR = MFMA16(al, bh, accR);
        }
    }
    // bias + relu -> sh (rows 0..31, cols 0..63); waves disjoint in (rg, ch)
    {
        int col = ch * 16 + m;
        float bb = (col < HD) ? b1[col] : 0.f;
        vf4 acc = accP + accQ + accR;
        #pragma unroll
        for (int r = 0; r < 4; ++r)
            sh[(rg * 16 + quad * 4 + r) * 68 + col] = fmaxf(acc[r] + bb, 0.f);
    }
    __syncthreads();

    // phase B A-frags: row = rg*16+m, k = ks*32+quad*8..+8
    bfrag ah2[2], al2[2];
    #pragma unroll
    for (int ks = 0; ks < 2; ++ks) {
        const float4* shp = (const float4*)&sh[(rg * 16 + m) * 68 + ks * 32 + quad * 8];
        float4 ha = shp[0], hb = shp[1];
        float hv[8] = {ha.x, ha.y, ha.z, ha.w, hb.x, hb.y, hb.z, hb.w};
        split8(hv, ah2[ks], al2[ks]);
    }
    __syncthreads();                             // all sh reads done; C reusable

    // phase B: fx -> LDS tiles [32][136] (hi in C, lo in B; B=sW1 is free)
    unsigned short* fxhiT = (unsigned short*)shC;
    unsigned short* fxloT = (unsigned short*)B4;
    #pragma unroll
    for (int nt2 = 0; nt2 < 2; ++nt2) {
        int nt = ch * 2 + nt2;
        bfrag bh0 = *(const bfrag*)&sW2[(nt * 2 + 0) * 64 + lane];
        bfrag bl0 = *(const bfrag*)&sW2[1024 + (nt * 2 + 0) * 64 + lane];
        bfrag bh1 = *(const bfrag*)&sW2[(nt * 2 + 1) * 64 + lane];
        bfrag bl1 = *(const bfrag*)&sW2[1024 + (nt * 2 + 1) * 64 + lane];
        vf4 aA = {0.f, 0.f, 0.f, 0.f}, aB = {0.f, 0.f, 0.f, 0.f};
        aA = MFMA16(ah2[0], bh0, aA);
        aA = MFMA16(ah2[0], bl0, aA);
        aA = MFMA16(al2[0], bh0, aA);
        aB = MFMA16(ah2[1], bh1, aB);
        aB = MFMA16(ah2[1], bl1, aB);
        aB = MFMA16(al2[1], bh1, aB);
        vf4 a2 = aA + aB;
        int colB = nt * 16 + m;
        float bb2 = b2[colB];
        #pragma unroll
        for (int r = 0; r < 4; ++r) {
            int row = rg * 16 + quad * 4 + r;
            float v = a2[r] + bb2;
            unsigned int u = __float_as_uint(v);
            unsigned short hh = (unsigned short)(u >> 16);   // trunc split
            fxhiT[row * 136 + colB] = hh;
            fxloT[row * 136 + colB] = bf16_rn(v - bf16_f(hh));
        }
    }
    __syncthreads();

    // =================== Stage F (round-3 k_fused geometry) =================
    int eh = ch;
    bfrag a_hi[4], a_lo[4];
    #pragma unroll
    for (int kb = 0; kb < 4; ++kb) {
        a_hi[kb] = *(const bfrag*)&fxhiT[(rg * 16 + m) * 136 + kb * 32 + quad * 8];
        a_lo[kb] = *(const bfrag*)&fxloT[(rg * 16 + m) * 136 + kb * 32 + quad * 8];
    }
    __syncthreads();                             // frag reads done; A/B reusable

    uint4* sWhi = A4;
    uint4* sWlo = B4;
    const uint4* gh = (const uint4*)(Wst_hi + (size_t)cat * ZD * ZD);
    const uint4* gl = (const uint4*)(Wst_lo + (size_t)cat * ZD * ZD);
    #pragma unroll
    for (int f = 0; f < 4; ++f) {
        int idx = tid + f * 512;
        int e = idx >> 4, q = idx & 15;
        sWhi[e * 17 + q] = gh[idx];
        sWlo[e * 17 + q] = gl[idx];
    }
    __syncthreads();

    // phase U: wave owns et = eh*2 + {0,1}; 3 independent chains each
    vf4 uacc[2];
    #pragma unroll 1
    for (int et2 = 0; et2 < 2; ++et2) {
        int et = eh * 2 + et2;
        vf4 aH = {0.f, 0.f, 0.f, 0.f};
        vf4 aM = {0.f, 0.f, 0.f, 0.f};
        vf4 aL = {0.f, 0.f, 0.f, 0.f};
        #pragma unroll
        for (int kb = 0; kb < 4; ++kb) {
            bfrag bh = *(const bfrag*)&sWhi[(et * 16 + m) * 17 + kb * 4 + quad];
            bfrag bl = *(const bfrag*)&sWlo[(et * 16 + m) * 17 + kb * 4 + quad];
            aH = MFMA16(a_hi[kb], bh, aH);
            aM = MFMA16(a_hi[kb], bl, aM);
            aL = MFMA16(a_lo[kb], bh, aL);
        }
        uacc[et2] = aH + aM + aL;
    }

    int nrow[4];
    #pragma unroll
    for (int r = 0; r < 4; ++r) {
        int ir = rg * 16 + quad * 4 + r;
        nrow[r] = (ir < mI) ? grouped[off + i0 + ir] : -1;
    }
    // phase T: batched fz prefetch, partial over wave's 2 et
    float fzv[2][4];
    #pragma unroll
    for (int et2 = 0; et2 < 2; ++et2) {
        #pragma unroll
        for (int r = 0; r < 4; ++r) {
            fzv[et2][r] = 0.f;
            if (nrow[r] >= 0)
                fzv[et2][r] = fz[(size_t)nrow[r] * ZD + (eh * 2 + et2) * 16 + m];
        }
    }
    float p[4] = {0.f, 0.f, 0.f, 0.f};
    #pragma unroll
    for (int et2 = 0; et2 < 2; ++et2) {
        #pragma unroll
        for (int r = 0; r < 4; ++r) p[r] += uacc[et2][r] * fzv[et2][r];
    }
    #pragma unroll
    for (int r = 0; r < 4; ++r) {
        float v = p[r];
        #pragma unroll
        for (int s = 8; s >= 1; s >>= 1) v += __shfl_xor(v, s, 64);
        p[r] = v;
    }
    if (m == 0) {
        #pragma unroll
        for (int r = 0; r < 4; ++r)
            sRedF[(rg * 4 + eh) * 16 + quad * 4 + r] = p[r];
    }
    __syncthreads();                             // pT visible; A free -> su

    unsigned short* su = (unsigned short*)A4;    // [row][e], stride 136
    #pragma unroll
    for (int et2 = 0; et2 < 2; ++et2) {
        int col = (eh * 2 + et2) * 16 + m;
        #pragma unroll
        for (int r = 0; r < 4; ++r)
            su[(rg * 16 + quad * 4 + r) * 136 + col] = bf16_rn(uacc[et2][r]);
    }
    float logT_r[4] = {0.f, 0.f, 0.f, 0.f};
    if (eh == 0) {
        #pragma unroll
        for (int r = 0; r < 4; ++r) {
            float pt = sRedF[(rg * 4 + 0) * 16 + quad * 4 + r]
                     + sRedF[(rg * 4 + 1) * 16 + quad * 4 + r]
                     + sRedF[(rg * 4 + 2) * 16 + quad * 4 + r]
                     + sRedF[(rg * 4 + 3) * 16 + quad * 4 + r];
            logT_r[r] = logf(softplus_acc(pt) + EPSF);
        }
    }
    __syncthreads();                             // su visible

    bfrag na[4];
    #pragma unroll
    for (int kb = 0; kb < 4; ++kb)
        na[kb] = *(const bfrag*)&su[(rg * 16 + m) * 136 + kb * 32 + quad * 8];

    uint4* sB = B4;                              // [64][17]; B free after U
    float negsum[4] = {0.f, 0.f, 0.f, 0.f};
    int jr_s = tid >> 4, q_s = tid & 15;         // staging row/col

    // prefetch j-tile 0 into regs (static indices)
    uint4 pf0, pf1;
    {
        int mJ0 = min(64, cnt);
        uint4 v0 = {0u, 0u, 0u, 0u}, v1 = {0u, 0u, 0u, 0u};
        if (jr_s < mJ0) {
            int j_g = grouped[off + jr_s];
            v0 = *(const uint4*)(fz_hi + (size_t)j_g * ZD + q_s * 8);
        }
        if (jr_s + 32 < mJ0) {
            int j_g = grouped[off + jr_s + 32];
            v1 = *(const uint4*)(fz_hi + (size_t)j_g * ZD + q_s * 8);
        }
        pf0 = v0; pf1 = v1;
    }

    #pragma unroll 1
    for (int jb = 0; jb < cnt; jb += 64) {
        int mJ = min(64, cnt - jb);
        __syncthreads();                         // prev tile's sB reads done
        sB[jr_s * 17 + q_s]        = pf0;
        sB[(jr_s + 32) * 17 + q_s] = pf1;
        // issue next tile's gather chain (overlaps this tile's compute)
        int jn = jb + 64;
        if (jn < cnt) {
            int mJn = min(64, cnt - jn);
            uint4 v0 = {0u, 0u, 0u, 0u}, v1 = {0u, 0u, 0u, 0u};
            if (jr_s < mJn) {
                int j_g = grouped[off + jn + jr_s];
                v0 = *(const uint4*)(fz_hi + (size_t)j_g * ZD + q_s * 8);
            }
            if (jr_s + 32 < mJn) {
                int j_g = grouped[off + jn + jr_s + 32];
                v1 = *(const uint4*)(fz_hi + (size_t)j_g * ZD + q_s * 8);
            }
            pf0 = v0; pf1 = v1;
        }
        __syncthreads();
        {
            int jt = eh;                         // wave owns one 16-wide j-tile
            bfrag b0 = *(const bfrag*)&sB[(jt * 16 + m) * 17 + 0 + quad];
            bfrag b1 = *(const bfrag*)&sB[(jt * 16 + m) * 17 + 4 + quad];
            bfrag b2 = *(const bfrag*)&sB[(jt * 16 + m) * 17 + 8 + quad];
            bfrag b3 = *(const bfrag*)&sB[(jt * 16 + m) * 17 + 12 + quad];
            vf4 aA = {0.f, 0.f, 0.f, 0.f}, aB = {0.f, 0.f, 0.f, 0.f};
            aA = MFMA16(na[0], b0, aA);
            aA = MFMA16(na[1], b1, aA);
            aB = MFMA16(na[2], b2, aB);
            aB = MFMA16(na[3], b3, aB);
            vf4 acc = aA + aB;
            bool jok = (jt * 16 + m) < mJ;
            #pragma unroll
            for (int r = 0; r < 4; ++r)
                if (jok) negsum[r] += softplus_hot(acc[r]);
        }
    }

    #pragma unroll
    for (int r = 0; r < 4; ++r) {
        float v = negsum[r];
        #pragma unroll
        for (int s = 8; s >= 1; s >>= 1) v += __shfl_xor(v, s, 64);
        negsum[r] = v;
    }
    if (m == 0) {
        #pragma unroll
        for (int r = 0; r < 4; ++r)
            sRedF[(rg * 4 + eh) * 16 + quad * 4 + r] = negsum[r];
    }
    __syncthreads();
    if (eh == 0 && m == 0) {
        #pragma unroll
        for (int r = 0; r < 4; ++r) {
            if (nrow[r] >= 0) {
                float tot = sRedF[(rg * 4 + 0) * 16 + quad * 4 + r]
                          + sRedF[(rg * 4 + 1) * 16 + quad * 4 + r]
                          + sRedF[(rg * 4 + 2) * 16 + quad * 4 + r]
                          + sRedF[(rg * 4 + 3) * 16 + quad * 4 + r];
                out[nrow[r]] = logT_r[r] - logf(tot / (float)cnt + EPSF);
            }
        }
    }
}

extern "C" void kernel_launch(void* const* d_in, const int* in_sizes, int n_in,
                              void* d_out, int out_size, void* d_ws, size_t ws_size,
                              hipStream_t stream) {
    const float* x  = (const float*)d_in[0];
    const int*   c  = (const int*)  d_in[1];
    const float* z  = (const float*)d_in[2];
    const float* W1 = (const float*)d_in[3];
    const float* b1 = (const float*)d_in[4];
    const float* W2 = (const float*)d_in[5];
    const float* b2 = (const float*)d_in[6];
    const float* Wz = (const float*)d_in[7];
    const float* bz = (const float*)d_in[8];
    const float* Ws = (const float*)d_in[9];
    float* out = (float*)d_out;

    uint4* W1p = (uint4*)d_ws;                         // 8192 uint4 (128 KB)
    uint4* W2p = W1p + 8192;                           // 2048 uint4 (32 KB)
    float* fz  = (float*)(W2p + 2048);                 // N*128 f
    unsigned short* fz_hi  = (unsigned short*)(fz + (size_t)N_ * ZD);
    unsigned short* Wst_hi = fz_hi + (size_t)N_ * ZD;  // CC*128*128
    unsigned short* Wst_lo = Wst_hi + (size_t)CC * ZD * ZD;
    int* counts  = (int*)(Wst_lo + (size_t)CC * ZD * ZD);
    int* offsets = counts + CC;
    int* grouped = offsets + CC;

    k_pre <<<276, 256, 0, stream>>>(c, W1, z, Wz, bz, W2, Ws, W1p, W2p, fz,
                                    fz_hi, Wst_hi, Wst_lo, counts, offsets,
                                    grouped);
    k_all <<<CC * TI, 512, 0, stream>>>(x, W1p, W2p, b1, b2, Wst_hi, Wst_lo,
                                        fz, fz_hi, grouped, offsets, counts,
                                        out);
}